// Round 8
// baseline (282.774 us; speedup 1.0000x reference)
//
#include <hip/hip_runtime.h>
#include <hip/hip_bf16.h>

typedef __bf16 bf16x8 __attribute__((ext_vector_type(8)));
typedef float f32x4 __attribute__((ext_vector_type(4)));

#define MFMA16(a,b,c) __builtin_amdgcn_mfma_f32_16x16x32_bf16(a,b,c,0,0,0)
#define GLL16(src, dst) __builtin_amdgcn_global_load_lds( \
    (const __attribute__((address_space(1))) unsigned int*)(src), \
    (__attribute__((address_space(3))) unsigned int*)(dst), 16, 0, 0)

__device__ inline unsigned int pack_bf16(float a, float b) {
    unsigned short ua = __builtin_bit_cast(unsigned short, (__bf16)a);
    unsigned short ub = __builtin_bit_cast(unsigned short, (__bf16)b);
    return ((unsigned int)ub << 16) | ua;
}
__device__ inline short bf_s(float v) {
    __bf16 b = (__bf16)v;
    return __builtin_bit_cast(short, b);
}

// ---------------------------------------------------------------------------
// Fused fp32->bf16: x -> xb, Wq/Wk/Wv -> Wb rows [0,2048)/[2048,2560)/[2560,3072)
// ---------------------------------------------------------------------------
__global__ void cvt_all(const float* __restrict__ x,  const float* __restrict__ wq,
                        const float* __restrict__ wk, const float* __restrict__ wv,
                        __bf16* __restrict__ xb, __bf16* __restrict__ wb) {
    long i = (long)(blockIdx.x * blockDim.x + threadIdx.x) * 8;
    const float* src; __bf16* dst;
    if (i < 8388608)       { src = x  + i;              dst = xb + i; }
    else if (i < 12582912) { src = wq + (i - 8388608);  dst = wb + (i - 8388608); }
    else if (i < 13631488) { src = wk + (i - 12582912); dst = wb + (i - 12582912 + 4194304); }
    else                   { src = wv + (i - 13631488); dst = wb + (i - 13631488 + 5242880); }
    float4 a = *(const float4*)src;
    float4 b = *(const float4*)(src + 4);
    bf16x8 r;
    r[0] = (__bf16)a.x; r[1] = (__bf16)a.y; r[2] = (__bf16)a.z; r[3] = (__bf16)a.w;
    r[4] = (__bf16)b.x; r[5] = (__bf16)b.y; r[6] = (__bf16)b.z; r[7] = (__bf16)b.w;
    *(bf16x8*)dst = r;
}

// ---------------------------------------------------------------------------
// Fused QKV GEMM (unchanged from R7): C = A·B^T, 128x128 tiles, 1-barrier
// double-buffered global_load_lds pipeline, frag-order LDS. Epilogue:
//   tn<16: Q row-major (x 128^-0.5); 16..19: K frag-order; 20..23: V frag-order.
// ---------------------------------------------------------------------------
__global__ __launch_bounds__(256) void gemm_qkv(const __bf16* __restrict__ A,
                                                const __bf16* __restrict__ B,
                                                __bf16* __restrict__ Qb,
                                                __bf16* __restrict__ Kf,
                                                __bf16* __restrict__ Vf,
                                                float qscale) {
    const int K = 2048;
    __shared__ __bf16 As[2 * 4096];
    __shared__ __bf16 Bs[2 * 4096];

    int tid = threadIdx.x;
    int wave = tid >> 6, lane = tid & 63;
    int quad = lane >> 4, l16 = lane & 15;

    int tm = blockIdx.x & 31, tn = blockIdx.x >> 5;

    const __bf16* Abase = A + (size_t)tm * 128 * K + (size_t)l16 * K + quad * 8;
    const __bf16* Bbase = B + (size_t)tn * 128 * K + (size_t)l16 * K + quad * 8;

    f32x4 acc[4][4] = {};

    auto stage = [&](int kt, int buf) {
#pragma unroll
        for (int rr = 0; rr < 2; ++rr) {
            int fb = rr * 4 + wave;
            GLL16(Abase + (size_t)fb * 16 * K + kt, As + buf * 4096 + fb * 512 + lane * 8);
            GLL16(Bbase + (size_t)fb * 16 * K + kt, Bs + buf * 4096 + fb * 512 + lane * 8);
        }
    };

    const int nk = K >> 5;
    stage(0, 0);
    for (int it = 0; it < nk; ++it) {
        __syncthreads();
        if (it + 1 < nk) stage((it + 1) << 5, (it + 1) & 1);
        const __bf16* Ab = As + (it & 1) * 4096;
        const __bf16* Bb = Bs + (it & 1) * 4096;
        bf16x8 af[4], bfr[4];
#pragma unroll
        for (int i = 0; i < 4; ++i)
            af[i] = *(const bf16x8*)(Ab + ((wave >> 1) * 4 + i) * 512 + lane * 8);
#pragma unroll
        for (int j = 0; j < 4; ++j)
            bfr[j] = *(const bf16x8*)(Bb + ((wave & 1) * 4 + j) * 512 + lane * 8);
#pragma unroll
        for (int i = 0; i < 4; ++i)
#pragma unroll
            for (int j = 0; j < 4; ++j)
                acc[i][j] = MFMA16(af[i], bfr[j], acc[i][j]);
    }

    int colbase = tn * 128 + (wave & 1) * 64;
#pragma unroll
    for (int i = 0; i < 4; ++i) {
        int row0 = tm * 128 + (wave >> 1) * 64 + i * 16 + quad * 4;
        int b = row0 >> 11, tok0 = row0 & 2047;
#pragma unroll
        for (int j = 0; j < 4; ++j) {
            int col = colbase + j * 16 + l16;
            if (tn < 16) {                       // ---- Q, row-major ----
#pragma unroll
                for (int r = 0; r < 4; ++r)
                    Qb[(size_t)(row0 + r) * 2048 + col] = (__bf16)(acc[i][j][r] * qscale);
            } else if (tn < 20) {                // ---- K frag-order ----
                int d_all = col - 2048;
                int g = d_all >> 7, dd = d_all & 127;
                int dt = dd >> 5, q4 = (dd >> 3) & 3, jj = dd & 7;
                int tb = tok0 >> 4, tl0 = tok0 & 15;
                __bf16* base = Kf + ((((size_t)(b * 4 + g) * 128 + tb) * 4 + dt) * 512)
                               + (q4 * 16 + tl0) * 8 + jj;
#pragma unroll
                for (int r = 0; r < 4; ++r)
                    base[r * 8] = (__bf16)acc[i][j][r];
            } else {                             // ---- V frag-order ----
                int d_all = col - 2560;
                int g = d_all >> 7, dd = d_all & 127;
                int nto = dd >> 4, dl = dd & 15;
                int ch = tok0 >> 6, kk = (tok0 >> 5) & 1;
                int q4v = (tok0 >> 3) & 3, jv0 = tok0 & 7;
                size_t off = ((((size_t)(b * 4 + g) * 32 + ch) * 16) + nto * 2 + kk) * 512
                             + (q4v * 16 + dl) * 8 + jv0;
                short4 pk;
                pk.x = bf_s(acc[i][j][0]); pk.y = bf_s(acc[i][j][1]);
                pk.z = bf_s(acc[i][j][2]); pk.w = bf_s(acc[i][j][3]);
                *(short4*)(Vf + off) = pk;
            }
        }
    }
}

// ---------------------------------------------------------------------------
// Flash attention, 1-barrier double-buffered K/V pipeline:
//   stage(0); loop { barrier; stage(ch+1)->buf^1; compute(ch,buf) }
// K/V staged via global_load_lds from frag-order arrays (coalesced 1KB/instr,
// lane-linear ds_read_b128 = conflict-free). V-frags hoisted: read ONCE per
// chunk (16 b128), shared across both mt accumulator rows. P: wave-private
// frag-order LDS round-trip (lgkmcnt-ordered, no barrier).
// LDS = 2*(16+16) + 8 = 72 KB -> 2 blocks/CU.
// ---------------------------------------------------------------------------
__global__ __launch_bounds__(256) void attn_mfma(const __bf16* __restrict__ Q,
                                                 const __bf16* __restrict__ Kf,
                                                 const __bf16* __restrict__ Vf,
                                                 float* __restrict__ O) {
    const int T = 2048, CM = 2048, HD = 128;
    __shared__ __bf16 Ks[2][8192];   // 2 x 16 KB, fb = t*4+dt
    __shared__ __bf16 Vs[2][8192];   // 2 x 16 KB, fb = nto*2+kk
    __shared__ __bf16 Pl[8192];      // 4 KB/wave, fb = mt*2+kk

    int tid = threadIdx.x;
    int wave = tid >> 6, lane = tid & 63;
    int quad = lane >> 4, l16 = lane & 15;

    int bg = blockIdx.x & 7;
    int slot = blockIdx.x >> 3;
    int qb = (slot < 32) ? (63 - slot) : (slot - 32);
    int b = bg >> 2, g = bg & 3;
    int h = g * 4 + wave;
    int q0 = qb * 32;

    bf16x8 qf[2][4];
    const __bf16* qbase = Q + (size_t)b * T * CM + (size_t)h * HD;
#pragma unroll
    for (int nt = 0; nt < 2; ++nt)
#pragma unroll
        for (int dt = 0; dt < 4; ++dt)
            qf[nt][dt] = *(const bf16x8*)(qbase + (size_t)(q0 + nt * 16 + l16) * CM
                                          + dt * 32 + quad * 8);

    const __bf16* kcb = Kf + (size_t)(b * 4 + g) * 262144 + wave * 2048 + lane * 8;
    const __bf16* vcb = Vf + (size_t)(b * 4 + g) * 262144 + wave * 2048 + lane * 8;

    float m_r[2] = {-1e30f, -1e30f}, l_r[2] = {0.f, 0.f};
    f32x4 o_acc[2][8] = {};
    __bf16* Pw = Pl + wave * 2048;

    auto stage = [&](int ch, int buf) {
        const __bf16* kg = kcb + ch * 8192;
        const __bf16* vg = vcb + ch * 8192;
        __bf16* kl = Ks[buf] + wave * 2048 + lane * 8;
        __bf16* vl = Vs[buf] + wave * 2048 + lane * 8;
#pragma unroll
        for (int i = 0; i < 4; ++i) GLL16(kg + i * 512, kl + i * 512);
#pragma unroll
        for (int i = 0; i < 4; ++i) GLL16(vg + i * 512, vl + i * 512);
    };

    int nch = (qb >> 1) + 1;
    stage(0, 0);
    for (int ch = 0; ch < nch; ++ch) {
        __syncthreads();   // drains stage(ch) (vmcnt0) + syncs buffer reuse
        if (ch + 1 < nch) stage(ch + 1, (ch + 1) & 1);
        const __bf16* Kb_ = Ks[ch & 1];
        const __bf16* Vb_ = Vs[ch & 1];

        // ---- S^T = K·Q^T ----
        f32x4 st[2][4] = {};
#pragma unroll
        for (int t = 0; t < 4; ++t)
#pragma unroll
            for (int dt = 0; dt < 4; ++dt) {
                bf16x8 kfv = *(const bf16x8*)(Kb_ + (t * 4 + dt) * 512 + lane * 8);
                st[0][t] = MFMA16(kfv, qf[0][dt], st[0][t]);
                st[1][t] = MFMA16(kfv, qf[1][dt], st[1][t]);
            }

        bool diag = (ch == nch - 1);
        float alpha[2];
#pragma unroll
        for (int nt = 0; nt < 2; ++nt) {
            if (diag) {
                int qg = q0 + nt * 16 + l16;
#pragma unroll
                for (int t = 0; t < 4; ++t)
#pragma unroll
                    for (int r = 0; r < 4; ++r)
                        if (ch * 64 + t * 16 + quad * 4 + r > qg) st[nt][t][r] = -1e30f;
            }
            float cmax = -1e30f;
#pragma unroll
            for (int t = 0; t < 4; ++t)
                cmax = fmaxf(cmax, fmaxf(fmaxf(st[nt][t][0], st[nt][t][1]),
                                         fmaxf(st[nt][t][2], st[nt][t][3])));
            cmax = fmaxf(cmax, __shfl_xor(cmax, 16));
            cmax = fmaxf(cmax, __shfl_xor(cmax, 32));
            float mnew = fmaxf(m_r[nt], cmax);
            alpha[nt] = __expf(m_r[nt] - mnew);
            m_r[nt] = mnew;
            float ps = 0.f;
#pragma unroll
            for (int t = 0; t < 4; ++t) {
                float p0 = __expf(st[nt][t][0] - mnew);
                float p1 = __expf(st[nt][t][1] - mnew);
                float p2 = __expf(st[nt][t][2] - mnew);
                float p3 = __expf(st[nt][t][3] - mnew);
                ps += (p0 + p1) + (p2 + p3);
                int off = (nt * 2 + (t >> 1)) * 512 + ((t & 1) * 2 + (quad >> 1)) * 128
                          + l16 * 8 + (quad & 1) * 4;
                unsigned long long pk =
                    (unsigned long long)pack_bf16(p0, p1) |
                    ((unsigned long long)pack_bf16(p2, p3) << 32);
                *(unsigned long long*)(Pw + off) = pk;
            }
            ps += __shfl_xor(ps, 16);
            ps += __shfl_xor(ps, 32);
            l_r[nt] = l_r[nt] * alpha[nt] + ps;
        }

        // ---- rescale O ----
#pragma unroll
        for (int mt = 0; mt < 2; ++mt)
#pragma unroll
            for (int r = 0; r < 4; ++r) {
                float alr = __shfl(alpha[mt], quad * 4 + r);
#pragma unroll
                for (int nto = 0; nto < 8; ++nto)
                    o_acc[mt][nto][r] *= alr;
            }

        // ---- O += P·V: preload P frags (4 b128), V frags read ONCE (16 b128)
        bf16x8 pf[2][2];
#pragma unroll
        for (int mt = 0; mt < 2; ++mt)
#pragma unroll
            for (int kk = 0; kk < 2; ++kk)
                pf[mt][kk] = *(const bf16x8*)(Pw + (mt * 2 + kk) * 512 + lane * 8);
#pragma unroll
        for (int kk = 0; kk < 2; ++kk)
#pragma unroll
            for (int nto = 0; nto < 8; ++nto) {
                bf16x8 vf = *(const bf16x8*)(Vb_ + (nto * 2 + kk) * 512 + lane * 8);
                o_acc[0][nto] = MFMA16(pf[0][kk], vf, o_acc[0][nto]);
                o_acc[1][nto] = MFMA16(pf[1][kk], vf, o_acc[1][nto]);
            }
    }

    float* obase = O + (size_t)b * T * CM + (size_t)h * HD;
#pragma unroll
    for (int mt = 0; mt < 2; ++mt) {
        float invl = 1.f / l_r[mt];
#pragma unroll
        for (int r = 0; r < 4; ++r) {
            float ir = __shfl(invl, quad * 4 + r);
            float* orow = obase + (size_t)(q0 + 16 * mt + quad * 4 + r) * CM;
#pragma unroll
            for (int nto = 0; nto < 8; ++nto)
                orow[nto * 16 + l16] = o_acc[mt][nto][r] * ir;
        }
    }
}

extern "C" void kernel_launch(void* const* d_in, const int* in_sizes, int n_in,
                              void* d_out, int out_size, void* d_ws, size_t ws_size,
                              hipStream_t stream) {
    const float* x  = (const float*)d_in[0];
    const float* Wq = (const float*)d_in[1];
    const float* Wk = (const float*)d_in[2];
    const float* Wv = (const float*)d_in[3];
    float* out = (float*)d_out;

    const float qscale = 0.08838834764831845f;  // 128^-0.5

    __bf16* xb = (__bf16*)d_ws;              // 8M elems
    __bf16* Wb = xb + 8388608;               // 6M  [3072][2048] = Wq|Wk|Wv
    __bf16* Qb = Wb + 6291456;               // 8M  [4096][2048]
    __bf16* Kfr = Qb + 8388608;              // 2M  frag-order K
    __bf16* Vfr = Kfr + 2097152;             // 2M  frag-order V

    cvt_all<<<7168, 256, 0, stream>>>(x, Wq, Wk, Wv, xb, Wb);
    gemm_qkv<<<768, 256, 0, stream>>>(xb, Wb, Qb, Kfr, Vfr, qscale);
    attn_mfma<<<512, 256, 0, stream>>>(Qb, Kfr, Vfr, out);
}